// Round 1
// baseline (31.550 us; speedup 1.0000x reference)
//
#include <hip/hip_runtime.h>

#define NB 8
#define NI 16
#define NO 16
#define ND 512

// Kernel 1: one block per (b,o). Computes, for each d:
//   rowv[bo,d]  = y2[b,o,d] + y5[b,o] + bias[o]
//   colv[bo,d]  = y3[b,o,d]
//   diagv[bo,d] = y1[b,o,d] + y4[b,o]
// where y4,y5 are reductions over d (done via wave shuffle + LDS).
__global__ __launch_bounds__(256) void leq_precompute(
    const float* __restrict__ x, const float* __restrict__ weight,
    const float* __restrict__ bias, float* __restrict__ rowv,
    float* __restrict__ colv, float* __restrict__ diagv)
{
    const int bo = blockIdx.x;      // 0..127
    const int b  = bo >> 4;         // / NO
    const int o  = bo & 15;
    const int t  = threadIdx.x;     // 0..255

    const float* wbase = weight + o * (5 * NI);   // [basis*16 + i]
    const float* xb    = x + b * (NI * ND);

    const int d0 = t, d1 = t + 256;
    float acc1a = 0.f, acc2a = 0.f, acc3a = 0.f;
    float acc1b = 0.f, acc2b = 0.f, acc3b = 0.f;
    float p4 = 0.f, p5 = 0.f;

    #pragma unroll
    for (int i = 0; i < NI; ++i) {
        const float w0 = wbase[0 * NI + i];
        const float w1 = wbase[1 * NI + i];
        const float w2 = wbase[2 * NI + i];
        const float w3 = wbase[3 * NI + i];
        const float w4 = wbase[4 * NI + i];
        const float xa = xb[i * ND + d0];
        const float xc = xb[i * ND + d1];
        acc1a += w0 * xa; acc2a += w1 * xa; acc3a += w2 * xa;
        acc1b += w0 * xc; acc2b += w1 * xc; acc3b += w2 * xc;
        const float xs = xa + xc;
        p4 += w3 * xs; p5 += w4 * xs;
    }

    // block-reduce p4,p5 over 256 threads (wave64 shuffle, then LDS across 4 waves)
    #pragma unroll
    for (int off = 32; off > 0; off >>= 1) {
        p4 += __shfl_down(p4, off, 64);
        p5 += __shfl_down(p5, off, 64);
    }
    __shared__ float red4[4], red5[4];
    const int wave = t >> 6, lane = t & 63;
    if (lane == 0) { red4[wave] = p4; red5[wave] = p5; }
    __syncthreads();
    const float y4 = red4[0] + red4[1] + red4[2] + red4[3];
    const float y5 = red5[0] + red5[1] + red5[2] + red5[3];

    const float base = y5 + bias[o];
    float* rv = rowv  + bo * ND;
    float* cv = colv  + bo * ND;
    float* dv = diagv + bo * ND;
    rv[d0] = acc2a + base; rv[d1] = acc2b + base;
    cv[d0] = acc3a;        cv[d1] = acc3b;
    dv[d0] = acc1a + y4;   dv[d1] = acc1b + y4;
}

// Kernel 2: streaming write of the (B,O,D,D) output, one float4 per thread.
// out[b,o,r,c] = rowv[bo,r] + colv[bo,c] + (r==c)*diagv[bo,r]
__global__ __launch_bounds__(256) void leq_write(
    const float* __restrict__ rowv, const float* __restrict__ colv,
    const float* __restrict__ diagv, float4* __restrict__ out)
{
    const int gid = blockIdx.x * 256 + threadIdx.x;   // < 8,388,608
    const int c4 = gid & 127;            // c / 4   (D/4 = 128)
    const int r  = (gid >> 7) & 511;
    const int bo = gid >> 16;            // / (D * D/4)

    const float rvd = rowv[(bo << 9) + r];
    const float dvv = diagv[(bo << 9) + r];
    const float4 cv = reinterpret_cast<const float4*>(colv)[(bo << 7) + c4];

    const int dcol = r - (c4 << 2);      // in [0,3] iff diagonal hits this float4
    float4 res;
    res.x = rvd + cv.x + ((dcol == 0) ? dvv : 0.0f);
    res.y = rvd + cv.y + ((dcol == 1) ? dvv : 0.0f);
    res.z = rvd + cv.z + ((dcol == 2) ? dvv : 0.0f);
    res.w = rvd + cv.w + ((dcol == 3) ? dvv : 0.0f);
    out[gid] = res;
}

extern "C" void kernel_launch(void* const* d_in, const int* in_sizes, int n_in,
                              void* d_out, int out_size, void* d_ws, size_t ws_size,
                              hipStream_t stream) {
    const float* x      = (const float*)d_in[0];
    const float* weight = (const float*)d_in[1];
    const float* bias   = (const float*)d_in[2];

    float* ws    = (float*)d_ws;
    float* rowv  = ws;
    float* colv  = ws + NB * NO * ND;
    float* diagv = ws + 2 * NB * NO * ND;

    leq_precompute<<<NB * NO, 256, 0, stream>>>(x, weight, bias, rowv, colv, diagv);

    const int total4 = NB * NO * ND * (ND / 4);   // 8,388,608 float4s
    leq_write<<<total4 / 256, 256, 0, stream>>>(rowv, colv, diagv, (float4*)d_out);
}

// Round 2
// 27.487 us; speedup vs baseline: 1.1478x; 1.1478x over previous
//
#include <hip/hip_runtime.h>

#define NB 8
#define NI 16
#define NO 16
#define ND 512
#define ROWS 32                      // output rows per block
#define RT   (ND / ROWS)             // 16 row-tiles per (b,o)

// One fused kernel. Block = (bo, row-tile). Each block redundantly recomputes
// the per-(b,o) vectors from x (256 KB total, L2-resident) into LDS, then
// streams its 32x512 output tile:
//   out[b,o,r,c] = y2[r] + y3[c] + y5 + bias[o] + (r==c)*(y1[r] + y4)
__global__ __launch_bounds__(256) void leq_fused(
    const float* __restrict__ x, const float* __restrict__ weight,
    const float* __restrict__ bias, float4* __restrict__ out)
{
    const int blk = blockIdx.x;          // 0..2047
    const int rt  = blk & (RT - 1);      // row tile within (b,o)
    const int bo  = blk >> 4;            // 0..127
    const int b   = bo >> 4;
    const int o   = bo & 15;
    const int t   = threadIdx.x;         // 0..255

    __shared__ __align__(16) float colvS[ND];   // y3 per c
    __shared__ float rowfS[ND];                 // y2 per d (full)
    __shared__ float diagfS[ND];                // y1 per d (full)
    __shared__ float rwS[ROWS], dgS[ROWS];      // finalized for this tile
    __shared__ float red4[4], red5[4];

    const float* wbase = weight + o * (5 * NI);
    const float* xb    = x + b * (NI * ND);

    const int d0 = t, d1 = t + 256;
    float a1a = 0.f, a2a = 0.f, a3a = 0.f;
    float a1b = 0.f, a2b = 0.f, a3b = 0.f;
    float p4 = 0.f, p5 = 0.f;

    #pragma unroll
    for (int i = 0; i < NI; ++i) {
        const float w0 = wbase[0 * NI + i];
        const float w1 = wbase[1 * NI + i];
        const float w2 = wbase[2 * NI + i];
        const float w3 = wbase[3 * NI + i];
        const float w4 = wbase[4 * NI + i];
        const float xa = xb[i * ND + d0];
        const float xc = xb[i * ND + d1];
        a1a += w0 * xa; a2a += w1 * xa; a3a += w2 * xa;
        a1b += w0 * xc; a2b += w1 * xc; a3b += w2 * xc;
        const float xs = xa + xc;
        p4 += w3 * xs; p5 += w4 * xs;
    }
    colvS[d0]  = a3a; colvS[d1]  = a3b;
    rowfS[d0]  = a2a; rowfS[d1]  = a2b;
    diagfS[d0] = a1a; diagfS[d1] = a1b;

    #pragma unroll
    for (int off = 32; off > 0; off >>= 1) {
        p4 += __shfl_down(p4, off, 64);
        p5 += __shfl_down(p5, off, 64);
    }
    const int wave = t >> 6, lane = t & 63;
    if (lane == 0) { red4[wave] = p4; red5[wave] = p5; }
    __syncthreads();

    const float y4 = red4[0] + red4[1] + red4[2] + red4[3];
    const float y5 = red5[0] + red5[1] + red5[2] + red5[3];
    const float base = y5 + bias[o];
    if (t < ROWS) {
        const int r = rt * ROWS + t;
        rwS[t] = rowfS[r] + base;   // y2[r] + y5 + bias
        dgS[t] = diagfS[r] + y4;    // y1[r] + y4
    }
    __syncthreads();

    const float4* colv4 = reinterpret_cast<const float4*>(colvS);
    const int out_base = bo * (ND * (ND / 4)) + rt * ROWS * (ND / 4);

    #pragma unroll 4
    for (int k = 0; k < ROWS * (ND / 4) / 256; ++k) {   // 16 iterations
        const int idx = k * 256 + t;
        const int c4  = idx & 127;          // c / 4
        const int rl  = idx >> 7;           // local row
        const int r   = rt * ROWS + rl;

        const float  rv = rwS[rl];
        const float  dv = dgS[rl];
        const float4 cv = colv4[c4];

        const int dcol = r - (c4 << 2);     // in [0,3] iff diagonal in this float4
        float4 res;
        res.x = rv + cv.x + ((dcol == 0) ? dv : 0.0f);
        res.y = rv + cv.y + ((dcol == 1) ? dv : 0.0f);
        res.z = rv + cv.z + ((dcol == 2) ? dv : 0.0f);
        res.w = rv + cv.w + ((dcol == 3) ? dv : 0.0f);
        out[out_base + idx] = res;
    }
}

extern "C" void kernel_launch(void* const* d_in, const int* in_sizes, int n_in,
                              void* d_out, int out_size, void* d_ws, size_t ws_size,
                              hipStream_t stream) {
    const float* x      = (const float*)d_in[0];
    const float* weight = (const float*)d_in[1];
    const float* bias   = (const float*)d_in[2];

    leq_fused<<<NB * NO * RT, 256, 0, stream>>>(x, weight, bias, (float4*)d_out);
}